// Round 1
// baseline (216.531 us; speedup 1.0000x reference)
//
#include <hip/hip_runtime.h>
#include <hip/hip_bf16.h>
#include <math.h>

typedef __bf16 bf16;
typedef __bf16 bf16x4 __attribute__((ext_vector_type(4)));
typedef __bf16 bf16x8 __attribute__((ext_vector_type(8)));
typedef float f32x4 __attribute__((ext_vector_type(4)));

#define DEV static __device__ __forceinline__

// B=2, S=2048, D=1024, H=16, hd=64, N_qkv=3072, M=B*S=4096
#define SS 2048
#define HH 16
#define HD 64

DEV void load_lds16(const bf16* g, bf16* l) {
  // dest must be wave-uniform base; HW adds lane*16B
  __builtin_amdgcn_global_load_lds(
      (const __attribute__((address_space(1))) unsigned int*)g,
      (__attribute__((address_space(3))) unsigned int*)l, 16, 0, 0);
}

// ---------------- fp32 -> bf16 straight convert (X) ----------------
__global__ void k_cvt(const float* __restrict__ in, bf16* __restrict__ out) {
  int i = (blockIdx.x * 256 + threadIdx.x) * 4;
  float4 v = *reinterpret_cast<const float4*>(in + i);
  bf16x4 o = {(bf16)v.x, (bf16)v.y, (bf16)v.z, (bf16)v.w};
  *reinterpret_cast<bf16x4*>(out + i) = o;
}

// ------------- fp32 [R,C] -> bf16 [C,R] tiled transpose -------------
__global__ void k_tr_f2b(const float* __restrict__ in, bf16* __restrict__ out,
                         int R, int C) {
  __shared__ float t[32][33];
  int ctile = blockIdx.x, rtile = blockIdx.y;
  int tx = threadIdx.x & 31, ty = threadIdx.x >> 5;  // 8 rows per sweep
#pragma unroll
  for (int i = 0; i < 4; ++i)
    t[ty + 8 * i][tx] = in[(rtile * 32 + ty + 8 * i) * C + ctile * 32 + tx];
  __syncthreads();
#pragma unroll
  for (int i = 0; i < 4; ++i) {
    int oc = ctile * 32 + ty + 8 * i;  // out row (= in col)
    out[oc * R + rtile * 32 + tx] = (bf16)t[tx][ty + 8 * i];
  }
}

// ---------------- shared GEMM mainloop (m97 structure) ----------------
// A [.,1024] bf16 row-major, Bt [.,1024] bf16 row-major (out-cols as rows).
// 128x128 tile, BK=64, 4 waves (2x2 of 64x64), acc 4x4 of 16x16.
DEV void gemm_core(const bf16* __restrict__ Ab, const bf16* __restrict__ Bb,
                   bf16* As, bf16* Bs, int w, int l, f32x4 acc[4][4]) {
  int fr = l & 15, fg = l >> 4;
  int wr = (w >> 1) * 64, wc = (w & 1) * 64;
  for (int kt = 0; kt < 16; ++kt) {
#pragma unroll
    for (int i = 0; i < 4; ++i) {
      int blk = w * 4 + i;  // 8 rows of 64 per 1KB chunk
      const bf16* ga = Ab + (blk * 8 + (l >> 3)) * 1024 + kt * 64 + (l & 7) * 8;
      const bf16* gb = Bb + (blk * 8 + (l >> 3)) * 1024 + kt * 64 + (l & 7) * 8;
      load_lds16(ga, As + blk * 512);
      load_lds16(gb, Bs + blk * 512);
    }
    __syncthreads();
#pragma unroll
    for (int kk = 0; kk < 2; ++kk) {
      bf16x8 af[4], bfv[4];
#pragma unroll
      for (int mi = 0; mi < 4; ++mi)
        af[mi] = *(const bf16x8*)(As + (wr + mi * 16 + fr) * 64 + kk * 32 + fg * 8);
#pragma unroll
      for (int ni = 0; ni < 4; ++ni)
        bfv[ni] = *(const bf16x8*)(Bs + (wc + ni * 16 + fr) * 64 + kk * 32 + fg * 8);
#pragma unroll
      for (int mi = 0; mi < 4; ++mi)
#pragma unroll
        for (int ni = 0; ni < 4; ++ni)
          acc[mi][ni] = __builtin_amdgcn_mfma_f32_16x16x32_bf16(
              af[mi], bfv[ni], acc[mi][ni], 0, 0, 0);
    }
    __syncthreads();
  }
}

// GEMM1: X @ Wqkv -> scatter into Q/K/V [B,H,S,64] bf16 (+bias)
__global__ __launch_bounds__(256) void k_gemm1(
    const bf16* __restrict__ A, const bf16* __restrict__ Bt,
    const float* __restrict__ bias, bf16* __restrict__ Qo,
    bf16* __restrict__ Ko, bf16* __restrict__ Vo) {
  __shared__ bf16 As[128 * 64], Bs[128 * 64];
  int wg = blockIdx.x;
  int bm = wg & 31, bn = wg >> 5;  // M/128=32, N/128=24
  int t = threadIdx.x, w = t >> 6, l = t & 63;
  f32x4 acc[4][4];
#pragma unroll
  for (int mi = 0; mi < 4; ++mi)
#pragma unroll
    for (int ni = 0; ni < 4; ++ni) acc[mi][ni] = (f32x4){0.f, 0.f, 0.f, 0.f};
  gemm_core(A + bm * 128 * 1024, Bt + bn * 128 * 1024, As, Bs, w, l, acc);
  int fr = l & 15, fg = l >> 4;
  int wr = (w >> 1) * 64, wc = (w & 1) * 64;
#pragma unroll
  for (int mi = 0; mi < 4; ++mi)
#pragma unroll
    for (int ni = 0; ni < 4; ++ni) {
      int gc = bn * 128 + wc + ni * 16 + fr;
      int sec = gc >> 10, cc = gc & 1023;
      bf16* dst = sec == 0 ? Qo : (sec == 1 ? Ko : Vo);
      int h = cc >> 6, d = cc & 63;
      float bb = bias[gc];
      int gr0 = bm * 128 + wr + mi * 16 + fg * 4;
#pragma unroll
      for (int r = 0; r < 4; ++r) {
        int gr = gr0 + r;
        int b = gr >> 11, s = gr & 2047;
        dst[((b * HH + h) * SS + s) * HD + d] = (bf16)(acc[mi][ni][r] + bb);
      }
    }
}

// GEMM2: heads @ Wo + bias -> fp32 out
__global__ __launch_bounds__(256) void k_gemm2(
    const bf16* __restrict__ A, const bf16* __restrict__ Bt,
    const float* __restrict__ bias, float* __restrict__ out) {
  __shared__ bf16 As[128 * 64], Bs[128 * 64];
  int wg = blockIdx.x;
  int bm = wg & 31, bn = wg >> 5;  // 32 x 8
  int t = threadIdx.x, w = t >> 6, l = t & 63;
  f32x4 acc[4][4];
#pragma unroll
  for (int mi = 0; mi < 4; ++mi)
#pragma unroll
    for (int ni = 0; ni < 4; ++ni) acc[mi][ni] = (f32x4){0.f, 0.f, 0.f, 0.f};
  gemm_core(A + bm * 128 * 1024, Bt + bn * 128 * 1024, As, Bs, w, l, acc);
  int fr = l & 15, fg = l >> 4;
  int wr = (w >> 1) * 64, wc = (w & 1) * 64;
#pragma unroll
  for (int mi = 0; mi < 4; ++mi)
#pragma unroll
    for (int ni = 0; ni < 4; ++ni) {
      int gc = bn * 128 + wc + ni * 16 + fr;
      float bb = bias[gc];
      int gr0 = bm * 128 + wr + mi * 16 + fg * 4;
#pragma unroll
      for (int r = 0; r < 4; ++r)
        out[(gr0 + r) * 1024 + gc] = acc[mi][ni][r] + bb;
    }
}

// ---------------- RoPE in-place on Q and K; Q *= 1/8 ----------------
__global__ void k_rope(bf16* __restrict__ Qb, bf16* __restrict__ Kb) {
  int t = blockIdx.x * 256 + threadIdx.x;  // 2 * 4194304/8 = 1048576
  bf16* buf = (t >> 19) ? Kb : Qb;
  float qs = (t >> 19) ? 1.0f : 0.125f;
  int g = t & 524287;         // [bh][s][j] , j = 8-elem group in dim
  int j = g & 7;
  int s = (g >> 3) & 2047;
  bf16* p = buf + (long long)g * 8;
  const float CN = -0.28782313662425572f;  // -2*ln(10000)/64
  float th0 = __expf(CN * (float)(2 * j));
  float th1 = __expf(CN * (float)(2 * j + 1));
  float sp = (float)s;
  float s0, c0, s1, c1;
  sincosf(sp * th0, &s0, &c0);
  sincosf(sp * th1, &s1, &c1);
  bf16x8 v = *(bf16x8*)p;
  float x[8];
#pragma unroll
  for (int i = 0; i < 8; ++i) x[i] = (float)v[i];
  float o[8];
  o[0] = x[0] * c0 - x[1] * s0; o[1] = x[0] * s0 + x[1] * c0;
  o[2] = x[2] * c0 - x[3] * s0; o[3] = x[2] * s0 + x[3] * c0;
  o[4] = x[4] * c1 - x[5] * s1; o[5] = x[4] * s1 + x[5] * c1;
  o[6] = x[6] * c1 - x[7] * s1; o[7] = x[6] * s1 + x[7] * c1;
  bf16x8 ov;
#pragma unroll
  for (int i = 0; i < 8; ++i) ov[i] = (bf16)(o[i] * qs);
  *(bf16x8*)p = ov;
}

// ------------- V [bh][2048][64] -> Vt [bh][64][2048] -------------
__global__ void k_trV(const bf16* __restrict__ V, bf16* __restrict__ Vt) {
  __shared__ bf16 t[64][66];
  int st = blockIdx.x, bh = blockIdx.y;
  const bf16* vb = V + (long long)bh * SS * HD;
  bf16* ob = Vt + (long long)bh * HD * SS;
  int tx = threadIdx.x & 63, ty = threadIdx.x >> 6;  // 4 rows/sweep
#pragma unroll
  for (int i = 0; i < 16; ++i)
    t[ty + 4 * i][tx] = vb[(st * 64 + ty + 4 * i) * 64 + tx];
  __syncthreads();
#pragma unroll
  for (int i = 0; i < 16; ++i) {
    int dR = ty + 4 * i;
    ob[dR * SS + st * 64 + tx] = t[tx][dR];
  }
}

// ---------------- flash attention, swapped-operand MFMA ----------------
// grid 512: 16 q-tiles x 32 bh. 4 waves x 32 q-rows. KV chunk = 32.
#define PSTR 40
__global__ __launch_bounds__(256) void k_attn(
    const bf16* __restrict__ Q, const bf16* __restrict__ K,
    const bf16* __restrict__ Vt, bf16* __restrict__ Hd) {
  __shared__ bf16 plds[4][2][16][PSTR];
  int wg = blockIdx.x;
  wg = (wg & 7) * 64 + (wg >> 3);  // XCD swizzle: 4 heads per XCD
  int qt = wg & 15, bh = wg >> 4;
  int b = bh >> 4, h = bh & 15;
  int t = threadIdx.x, w = t >> 6, l = t & 63;
  int fr = l & 15, fg = l >> 4;
  const bf16* Qb = Q + (long long)bh * SS * HD;
  const bf16* Kb = K + (long long)bh * SS * HD;
  const bf16* Vb = Vt + (long long)bh * HD * SS;
  int q0 = qt * 128 + w * 32;
  bf16x8 qf[2][2];
#pragma unroll
  for (int qs = 0; qs < 2; ++qs)
#pragma unroll
    for (int ds = 0; ds < 2; ++ds)
      qf[qs][ds] = *(const bf16x8*)(Qb + (q0 + qs * 16 + fr) * 64 + ds * 32 + fg * 8);
  f32x4 acc[4][2];
#pragma unroll
  for (int db = 0; db < 4; ++db)
#pragma unroll
    for (int qs = 0; qs < 2; ++qs) acc[db][qs] = (f32x4){0.f, 0.f, 0.f, 0.f};
  float m[2] = {-1e30f, -1e30f}, ssum[2] = {0.f, 0.f};
  const f32x4 zero = {0.f, 0.f, 0.f, 0.f};
  for (int kv = 0; kv < SS; kv += 32) {
    bf16x8 kf[2][2];
#pragma unroll
    for (int ks = 0; ks < 2; ++ks)
#pragma unroll
      for (int ds = 0; ds < 2; ++ds)
        kf[ks][ds] = *(const bf16x8*)(Kb + (kv + ks * 16 + fr) * 64 + ds * 32 + fg * 8);
    f32x4 stl[2][2];  // S^T: lane col = q (fr), rows = keys 4*fg+r (+16*ks)
#pragma unroll
    for (int ks = 0; ks < 2; ++ks)
#pragma unroll
      for (int qs = 0; qs < 2; ++qs) {
        stl[ks][qs] = __builtin_amdgcn_mfma_f32_16x16x32_bf16(kf[ks][0], qf[qs][0], zero, 0, 0, 0);
        stl[ks][qs] = __builtin_amdgcn_mfma_f32_16x16x32_bf16(kf[ks][1], qf[qs][1], stl[ks][qs], 0, 0, 0);
      }
#pragma unroll
    for (int qs = 0; qs < 2; ++qs) {
      float cm = stl[0][qs][0];
#pragma unroll
      for (int r = 1; r < 4; ++r) cm = fmaxf(cm, stl[0][qs][r]);
#pragma unroll
      for (int r = 0; r < 4; ++r) cm = fmaxf(cm, stl[1][qs][r]);
      cm = fmaxf(cm, __shfl_xor(cm, 16));
      cm = fmaxf(cm, __shfl_xor(cm, 32));
      if (cm > m[qs]) {
        float f = __expf(m[qs] - cm);
        m[qs] = cm;
        ssum[qs] *= f;
#pragma unroll
        for (int db = 0; db < 4; ++db) acc[db][qs] *= f;
      }
      float ps = 0.f;
      bf16x4 pb[2];
#pragma unroll
      for (int ks = 0; ks < 2; ++ks)
#pragma unroll
        for (int r = 0; r < 4; ++r) {
          float p = __expf(stl[ks][qs][r] - m[qs]);
          ps += p;
          pb[ks][r] = (bf16)p;
        }
      ssum[qs] += ps;
      *(bf16x4*)&plds[w][qs][fr][fg * 4] = pb[0];
      *(bf16x4*)&plds[w][qs][fr][16 + fg * 4] = pb[1];
    }
    bf16x8 pf[2];
#pragma unroll
    for (int qs = 0; qs < 2; ++qs)
      pf[qs] = *(const bf16x8*)&plds[w][qs][fr][fg * 8];
#pragma unroll
    for (int db = 0; db < 4; ++db) {
      bf16x8 vf = *(const bf16x8*)(Vb + (db * 16 + fr) * SS + kv + fg * 8);
#pragma unroll
      for (int qs = 0; qs < 2; ++qs)
        acc[db][qs] = __builtin_amdgcn_mfma_f32_16x16x32_bf16(vf, pf[qs], acc[db][qs], 0, 0, 0);
    }
  }
#pragma unroll
  for (int qs = 0; qs < 2; ++qs) {
    float sv = ssum[qs];
    sv += __shfl_xor(sv, 16);
    sv += __shfl_xor(sv, 32);
    float inv = 1.0f / sv;
    int s = q0 + qs * 16 + fr;
#pragma unroll
    for (int db = 0; db < 4; ++db) {
      bf16x4 ob;
#pragma unroll
      for (int r = 0; r < 4; ++r) ob[r] = (bf16)(acc[db][qs][r] * inv);
      *(bf16x4*)(Hd + ((long long)(b * SS + s)) * 1024 + h * 64 + db * 16 + fg * 4) = ob;
    }
  }
}

extern "C" void kernel_launch(void* const* d_in, const int* in_sizes, int n_in,
                              void* d_out, int out_size, void* d_ws, size_t ws_size,
                              hipStream_t stream) {
  const float* emb = (const float*)d_in[0];   // [2,2048,1024]
  const float* Wqkv = (const float*)d_in[1];  // [1024,3072]
  const float* bqkv = (const float*)d_in[2];  // [3072]
  const float* Wo = (const float*)d_in[3];    // [1024,1024]
  const float* bo = (const float*)d_in[4];    // [1024]
  float* out = (float*)d_out;
  char* ws = (char*)d_ws;
  bf16* Xb  = (bf16*)(ws);               // 8 MiB  [4096,1024]
  bf16* Wqt = (bf16*)(ws + 8388608);     // 6 MiB  [3072,1024]
  bf16* Wot = (bf16*)(ws + 14680064);    // 2 MiB  [1024,1024]
  bf16* Qb  = (bf16*)(ws + 16777216);    // 8 MiB  [32][2048][64]
  bf16* Kb  = (bf16*)(ws + 25165824);    // 8 MiB
  bf16* Vb  = (bf16*)(ws + 33554432);    // 8 MiB
  bf16* Vt  = (bf16*)(ws + 41943040);    // 8 MiB  [32][64][2048]
  bf16* Hd  = (bf16*)(ws + 50331648);    // 8 MiB  [4096,1024]

  hipLaunchKernelGGL(k_cvt, dim3(4096), dim3(256), 0, stream, emb, Xb);
  hipLaunchKernelGGL(k_tr_f2b, dim3(96, 32), dim3(256), 0, stream, Wqkv, Wqt, 1024, 3072);
  hipLaunchKernelGGL(k_tr_f2b, dim3(32, 32), dim3(256), 0, stream, Wo, Wot, 1024, 1024);
  hipLaunchKernelGGL(k_gemm1, dim3(768), dim3(256), 0, stream, Xb, Wqt, bqkv, Qb, Kb, Vb);
  hipLaunchKernelGGL(k_rope, dim3(4096), dim3(256), 0, stream, Qb, Kb);
  hipLaunchKernelGGL(k_trV, dim3(32, 32), dim3(256), 0, stream, Vb, Vt);
  hipLaunchKernelGGL(k_attn, dim3(512), dim3(256), 0, stream, Qb, Kb, Vt, Hd);
  hipLaunchKernelGGL(k_gemm2, dim3(256), dim3(256), 0, stream, Hd, Wot, bo, out);
}